// Round 3
// baseline (315.445 us; speedup 1.0000x reference)
//
#include <hip/hip_runtime.h>
#include <hip/hip_bf16.h>

#define B_    16
#define M_    4096
#define K_    512
#define O_    512

#define BM 128
#define BN 128
#define BK 32

typedef float f32x4 __attribute__((ext_vector_type(4)));
typedef short bf16x8 __attribute__((ext_vector_type(8)));
typedef unsigned short u16x8 __attribute__((ext_vector_type(8)));

// LDS chunk swizzle (verified 0-conflict in R2): tile = 128 rows x 4 k-quads
// of 16B chunks; chunk(row,kq) = row*4 + (kq ^ ((row>>1)&3)).
__device__ __forceinline__ int chunk_off(int row, int kq) {
    return (row * 4 + (kq ^ ((row >> 1) & 3))) * 8;   // ushort offset
}

// ---------------- kernel 1: s[b,i] = sum_f w[b,f]*A_w[i,f] + A_b[i] ----------------
__global__ void style_kernel(const float* __restrict__ w, const float* __restrict__ A_w,
                             const float* __restrict__ A_b, float* __restrict__ s) {
    int b = blockIdx.x;
    int i = blockIdx.y * 64 + threadIdx.x;
    __shared__ float wsh[512];
    for (int j = threadIdx.x; j < 512; j += 64) wsh[j] = w[b * 512 + j];
    __syncthreads();
    const float* arow = A_w + (size_t)i * 512;
    float acc = 0.f;
    #pragma unroll 4
    for (int f = 0; f < 512; f += 4) {
        float4 a = *(const float4*)(arow + f);
        acc += a.x * wsh[f] + a.y * wsh[f + 1] + a.z * wsh[f + 2] + a.w * wsh[f + 3];
    }
    s[b * 512 + i] = acc + A_b[i];
}

// ---------------- kernel 2: nrm[b,o] = rsqrt(eps + sum_i (weight[o,i]*s[b,i])^2) ----
__global__ void nrm_kernel(const float* __restrict__ weight, const float* __restrict__ s,
                           float* __restrict__ nrm) {
    int gw = blockIdx.x * 4 + (threadIdx.x >> 6);
    int lane = threadIdx.x & 63;
    int b = gw >> 9;
    int o = gw & 511;
    const float* wrow = weight + (size_t)o * 512;
    const float* srow = s + b * 512;
    float ss = 0.f;
    #pragma unroll
    for (int j = 0; j < 8; j++) {
        int i = lane + j * 64;
        float v = wrow[i] * srow[i];
        ss += v * v;
    }
    #pragma unroll
    for (int off = 32; off; off >>= 1) ss += __shfl_xor(ss, off);
    if (lane == 0) nrm[b * 512 + o] = rsqrtf(1e-8f + ss);
}

// ---------------- kernel 3: weight -> bf16 ----------------
__global__ void wcast_kernel(const float* __restrict__ weight, unsigned short* __restrict__ wb) {
    int e = (blockIdx.x * 256 + threadIdx.x) * 4;
    float4 v = *(const float4*)(weight + e);
    union { __hip_bfloat162 h[2]; unsigned long long u; } cv;
    cv.h[0] = __float22bfloat162_rn(float2{v.x, v.y});
    cv.h[1] = __float22bfloat162_rn(float2{v.z, v.w});
    *(unsigned long long*)(wb + e) = cv.u;
}

// ---------------- kernel 4: out[b,n,o] = relu( nrm[b,o]*((x[b].s[b]) @ wbf^T) + bias ) ----
// Register-staged, single barrier per K-iter, loads stay in flight across barriers.
__global__ __launch_bounds__(256, 4) void gemm_kernel(const float* __restrict__ x,
                                                      const unsigned short* __restrict__ wb,
                                                      const float* __restrict__ s,
                                                      const float* __restrict__ nrm,
                                                      const float* __restrict__ bias,
                                                      float* __restrict__ out) {
    __shared__ unsigned short sA[2][BM * BK];
    __shared__ unsigned short sB[2][BN * BK];
    __shared__ float sS[K_];

    // XCD swizzle (kept from R2: FETCH 270->70MB)
    int g = blockIdx.x;
    int xcd = g & 7;
    int grp = g >> 3;
    int nblk = grp & 3;
    int mb = xcd * 64 + (grp >> 2);
    const int b  = mb >> 5;
    const int m0 = (mb & 31) * BM;
    const int n0 = nblk * BN;

    const float* xb = x + (size_t)b * M_ * K_;

    const int t = threadIdx.x;
    const int w = t >> 6;
    const int l = t & 63;
    const int wave_row = (w >> 1) * 64;
    const int wave_col = (w & 1) * 64;
    const int lrow  = l & 15;
    const int kq_l  = l >> 4;

    // stage s[b,:] into LDS (512 floats)
    *(float2*)(&sS[t * 2]) = *(const float2*)(s + b * K_ + t * 2);

    int offA[4], offB[4];
    #pragma unroll
    for (int mi = 0; mi < 4; mi++) offA[mi] = chunk_off(wave_row + mi * 16 + lrow, kq_l);
    #pragma unroll
    for (int ni = 0; ni < 4; ni++) offB[ni] = chunk_off(wave_col + ni * 16 + lrow, kq_l);

    // staging geometry: thread t covers row t>>1, 16 elements at col (t&1)*16
    const int ar = t >> 1;
    const int aq = t & 1;
    const float* abase = xb + (size_t)(m0 + ar) * K_ + aq * 16;
    const unsigned short* bbase = wb + (size_t)(n0 + ar) * K_ + aq * 16;

    f32x4 araw[4];
    u16x8 braw[2];
    #pragma unroll
    for (int j = 0; j < 4; j++) araw[j] = *(const f32x4*)(abase + j * 4);
    #pragma unroll
    for (int j = 0; j < 2; j++) braw[j] = *(const u16x8*)(bbase + j * 8);

    __syncthreads();   // sS visible before first use

    f32x4 acc[4][4] = {};

    #pragma unroll 2
    for (int i = 0; i < 16; i++) {
        const int kk = i * BK;
        const int buf = i & 1;

        // stage tile i into LDS (consume raw regs), folding s into A (fp32)
        #pragma unroll
        for (int j = 0; j < 2; j++) {
            f32x4 s0 = *(const f32x4*)(&sS[kk + aq * 16 + j * 8]);
            f32x4 s1 = *(const f32x4*)(&sS[kk + aq * 16 + j * 8 + 4]);
            f32x4 p0 = araw[2 * j] * s0;
            f32x4 p1 = araw[2 * j + 1] * s1;
            union { __hip_bfloat162 h[4]; u16x8 v; } cv;
            cv.h[0] = __float22bfloat162_rn(float2{p0[0], p0[1]});
            cv.h[1] = __float22bfloat162_rn(float2{p0[2], p0[3]});
            cv.h[2] = __float22bfloat162_rn(float2{p1[0], p1[1]});
            cv.h[3] = __float22bfloat162_rn(float2{p1[2], p1[3]});
            *(u16x8*)(&sA[buf][chunk_off(ar, aq * 2 + j)]) = cv.v;
        }
        #pragma unroll
        for (int j = 0; j < 2; j++)
            *(u16x8*)(&sB[buf][chunk_off(ar, aq * 2 + j)]) = braw[j];

        // issue loads for tile i+1 — plain register loads: NOT drained at barrier
        if (i < 15) {
            #pragma unroll
            for (int j = 0; j < 4; j++) araw[j] = *(const f32x4*)(abase + kk + BK + j * 4);
            #pragma unroll
            for (int j = 0; j < 2; j++) braw[j] = *(const u16x8*)(bbase + kk + BK + j * 8);
        }

        __syncthreads();   // lgkm drain only (ds_writes); global loads stay in flight

        bf16x8 af[4], bfr[4];
        #pragma unroll
        for (int mi = 0; mi < 4; mi++) af[mi] = *(const bf16x8*)(&sA[buf][offA[mi]]);
        #pragma unroll
        for (int ni = 0; ni < 4; ni++) bfr[ni] = *(const bf16x8*)(&sB[buf][offB[ni]]);
        #pragma unroll
        for (int mi = 0; mi < 4; mi++)
            #pragma unroll
            for (int ni = 0; ni < 4; ni++)
                acc[mi][ni] = __builtin_amdgcn_mfma_f32_16x16x32_bf16(af[mi], bfr[ni], acc[mi][ni], 0, 0, 0);
        // no trailing barrier: next iter writes buf^1; re-write of buf is gated
        // by next iter's barrier (hazard-checked)
    }

    // epilogue: C/D layout col=lane&15, row=(lane>>4)*4+reg  [m89-verified]
    const int col_l = l & 15;
    const int row_q = (l >> 4) * 4;
    #pragma unroll
    for (int ni = 0; ni < 4; ni++) {
        int o = n0 + wave_col + ni * 16 + col_l;
        float bv = bias[o];
        float nv = nrm[b * 512 + o];
        #pragma unroll
        for (int mi = 0; mi < 4; mi++) {
            int mrow = m0 + wave_row + mi * 16 + row_q;
            #pragma unroll
            for (int r = 0; r < 4; r++) {
                float v = acc[mi][ni][r] * nv + bv;
                out[((size_t)b * M_ + mrow + r) * O_ + o] = v > 0.f ? v : 0.f;
            }
        }
    }
}

extern "C" void kernel_launch(void* const* d_in, const int* in_sizes, int n_in,
                              void* d_out, int out_size, void* d_ws, size_t ws_size,
                              hipStream_t stream) {
    const float* x      = (const float*)d_in[0];
    const float* w      = (const float*)d_in[1];
    const float* weight = (const float*)d_in[2];
    const float* bias   = (const float*)d_in[3];
    const float* A_w    = (const float*)d_in[4];
    const float* A_b    = (const float*)d_in[5];
    float* out = (float*)d_out;

    unsigned short* wbf = (unsigned short*)d_ws;                     // 512 KB
    float* s   = (float*)((char*)d_ws + 512 * 1024);                 // 32 KB
    float* nrm = (float*)((char*)d_ws + 512 * 1024 + 32 * 1024);     // 32 KB

    style_kernel<<<dim3(B_, 8), 64, 0, stream>>>(w, A_w, A_b, s);
    wcast_kernel<<<(O_ * K_) / 1024, 256, 0, stream>>>(weight, wbf);
    nrm_kernel<<<(B_ * O_) / 4, 256, 0, stream>>>(weight, s, nrm);
    gemm_kernel<<<2048, 256, 0, stream>>>(x, wbf, s, nrm, bias, out);
}